// Round 8
// baseline (466.853 us; speedup 1.0000x reference)
//
#include <hip/hip_runtime.h>
#include <stdint.h>

// Self-attention, SEQ=8192, D=768, single head.
//   K0a: x fp32->bf16; K0b: Wq/Wk/Wv fp32->bf16 (z-fused)
//   K1a: Q,K projections z-fused (128^2 engine, MODE 0)
//   K1b: Vt = Wv x^T (128^2, MODE 0)
//   K2 : P' = exp(Q K^T) bf16 + rowsums     (256^2 8-phase, MODE 1)
//   K3 : out += (P' V)/rowsum, split-K x8   (256^2 8-phase, MODE 2)  <- R18
//
// R18: R17's 8-phase engine measured 164->129 us on K2 (628->800 TF) with
// the re-derived invariants (16x16x32 -> 8 acc chains; vmcnt(6)=3 half-tile
// flight; register-held operands). K3 (157 us on the 128^2 engine) is now
// the top dispatch -> port it onto the SAME engine (K-loop byte-identical,
// only epilogue + kOff differ). Split-K 4->8: 768 blocks = 3/CU balanced
// (vs 384 = half the CUs doing 2x work at 2-resident); atomic traffic
// 98->197 MB costs ~12 us, balance saves ~25.

#define SEQ    8192
#define DMODEL 768
#define KSPLIT 8             // split-K for K3 (256^2 engine)
#define LROW   64            // 128^2 engine LDS row stride (halfwords)

typedef short bf16x8 __attribute__((ext_vector_type(8)));
typedef float f32x4  __attribute__((ext_vector_type(4)));
typedef float f32x16 __attribute__((ext_vector_type(16)));

__device__ __forceinline__ unsigned short f2bf(float f) {
  union { float f; unsigned int u; } v; v.f = f;
  unsigned int u = v.u;
  u += 0x7FFFu + ((u >> 16) & 1u);   // round-to-nearest-even
  return (unsigned short)(u >> 16);
}

// global -> LDS direct DMA, 16 B/lane; LDS dest wave-uniform + lane*16 (m104).
__device__ __forceinline__ void gload16(const unsigned short* g, unsigned short* l) {
  __builtin_amdgcn_global_load_lds(
      (const __attribute__((address_space(1))) unsigned int*)g,
      (__attribute__((address_space(3))) unsigned int*)l, 16, 0, 0);
}

// Stage one half-tile (128x64 bf16 = 16 KB): 512 thr x 2 x 16 B.
// LDS linear; source column pre-swizzled (slot j <- col j^(row&7)).
__device__ __forceinline__ void stage_ht(const unsigned short* __restrict__ g,
                                         int Kd, unsigned short* l, int t) {
  const int c0 = t, c1 = t + 512;
  const int r0 = c0 >> 3, r1 = c1 >> 3;
  const int s0 = ((c0 & 7) ^ (r0 & 7)) << 3;
  const int s1 = ((c1 & 7) ^ (r1 & 7)) << 3;
  gload16(g + (size_t)r0 * Kd + s0, l + (c0 << 3));
  gload16(g + (size_t)r1 * Kd + s1, l + (c1 << 3));
}

__global__ void convert_x(const float* __restrict__ src,
                          unsigned short* __restrict__ dst, int n4) {
  int i = blockIdx.x * blockDim.x + threadIdx.x;
  if (i >= n4) return;
  const float4 f = ((const float4*)src)[i];
  ushort4 o;
  o.x = f2bf(f.x); o.y = f2bf(f.y); o.z = f2bf(f.z); o.w = f2bf(f.w);
  ((ushort4*)dst)[i] = o;
}

__global__ void convert_w(const float* __restrict__ s0, const float* __restrict__ s1,
                          const float* __restrict__ s2,
                          unsigned short* __restrict__ d0, unsigned short* __restrict__ d1,
                          unsigned short* __restrict__ d2, int n4) {
  const float* s = (blockIdx.z == 0) ? s0 : (blockIdx.z == 1) ? s1 : s2;
  unsigned short* d = (blockIdx.z == 0) ? d0 : (blockIdx.z == 1) ? d1 : d2;
  int i = blockIdx.x * blockDim.x + threadIdx.x;
  if (i >= n4) return;
  const float4 f = ((const float4*)s)[i];
  ushort4 o;
  o.x = f2bf(f.x); o.y = f2bf(f.y); o.z = f2bf(f.z); o.w = f2bf(f.w);
  ((ushort4*)d)[i] = o;
}

// ---------------- 256^2 8-phase engine (K2 + K3) ----------------
// C[m,n]=sum_k A[m,k]B[n,k] (both row-major [rows][K]).
// 8 waves (2M x 4N); per-wave out = rows {qa*128+wrow*64+0..63} x cols
// {bh*128+wcol*32+0..31} (2x2 of 64x32). MFMA 16x16x32: A/B frag lane
// row=l&15, k=(l>>4)*8+j; C/D col=l&15, row=(l>>4)*4+reg [m89/m91].
// LDS halfwords: [dbuf2][tensor2][half2][128][64]=65536 (128 KB).
// Schedule (verified R17, K2 164->129 us): phases (qa, b-half) per K-tile,
// reads-once-into-regs, one 16KB stage/phase, vmcnt(6) only at ph4/ph8.
// MODE 1: writes exp(C) bf16 + atomic per-row exp-sums into rowsum.
// MODE 2: split-K over blockIdx.z (kChunk each); atomicAdd fp32 C/rowsum[m].
template <int MODE>
__launch_bounds__(512, 2)
__global__ void gemm256(const unsigned short* __restrict__ A,
                        const unsigned short* __restrict__ B,
                        void* __restrict__ Cout,
                        int N, int K, float* __restrict__ rowsum, int kChunk) {
  __shared__ __align__(16) unsigned short lds[65536];
  const int t    = threadIdx.x;
  const int w    = t >> 6, l = t & 63;
  const int lr   = l & 15, lq = l >> 4;
  const int wrow = w >> 2, wcol = w & 3;
  const int m0   = blockIdx.x * 256;
  const int n0   = blockIdx.y * 256;
  const int kOff = (MODE == 2) ? blockIdx.z * kChunk : 0;
  const unsigned short* Ab = A + (size_t)m0 * K + kOff;
  const unsigned short* Bb = B + (size_t)n0 * K + kOff;

  // hoisted read-address pieces: row_local*64 and swizzled k-chunk offsets
  const int rA64 = (wrow * 64 + lr) * 64;
  const int rB64 = (wcol * 32 + lr) * 64;
  const int x7   = lr & 7;
  const int csw0 = ((0 + lq) ^ x7) << 3;   // ks=0 chunk
  const int csw1 = ((4 + lq) ^ x7) << 3;   // ks=1 chunk

  f32x4 acc[2][2][4][2] = {};              // [qa][bh][rt][ct]
  const int nt = kChunk >> 6, ni = nt >> 1;

#define STG(T, H, D, JT) stage_ht(((T) ? Bb : Ab) + (size_t)((H) * 128) * K + (JT) * 64, K, \
                                  &lds[(D) * 32768 + (T) * 16384 + (H) * 8192], t)
#define RDA(D, QA) do { \
    _Pragma("unroll") for (int rt = 0; rt < 4; ++rt) { \
      a[rt][0] = *(const bf16x8*)&lds[(D)*32768 + (QA)*8192 + rA64 + rt*1024 + csw0]; \
      a[rt][1] = *(const bf16x8*)&lds[(D)*32768 + (QA)*8192 + rA64 + rt*1024 + csw1]; \
    } } while (0)
#define RDB(D, BH, DST) do { \
    _Pragma("unroll") for (int ct = 0; ct < 2; ++ct) { \
      DST[ct][0] = *(const bf16x8*)&lds[(D)*32768 + 16384 + (BH)*8192 + rB64 + ct*1024 + csw0]; \
      DST[ct][1] = *(const bf16x8*)&lds[(D)*32768 + 16384 + (BH)*8192 + rB64 + ct*1024 + csw1]; \
    } } while (0)
#define MM16(QA, BH, BR) do { \
    __builtin_amdgcn_s_setprio(1); \
    _Pragma("unroll") for (int ks = 0; ks < 2; ++ks) \
      _Pragma("unroll") for (int rt = 0; rt < 4; ++rt) \
        _Pragma("unroll") for (int ct = 0; ct < 2; ++ct) \
          acc[QA][BH][rt][ct] = __builtin_amdgcn_mfma_f32_16x16x32_bf16( \
              a[rt][ks], BR[ct][ks], acc[QA][BH][rt][ct], 0, 0, 0); \
    __builtin_amdgcn_s_setprio(0); \
  } while (0)
#define WAITV6() asm volatile("s_waitcnt vmcnt(6)" ::: "memory")
#define WAITV0() asm volatile("s_waitcnt vmcnt(0)" ::: "memory")
#define LGKM0()  asm volatile("s_waitcnt lgkmcnt(0)" ::: "memory")
#define BAR()    __builtin_amdgcn_s_barrier()

  bf16x8 a[4][2], b0[2][2], b1[2][2];

  // Prologue: tile0 (A0,B0,B1,A1)->d0, tile1 (A0,B0,B1)->d1; 7 slots,
  // drain to 3 -> tile0 resident, {A0,B0,B1}(1) in flight = loop invariant.
  STG(0, 0, 0, 0); STG(1, 0, 0, 0); STG(1, 1, 0, 0); STG(0, 1, 0, 0);
  STG(0, 0, 1, 1); STG(1, 0, 1, 1); STG(1, 1, 1, 1);
  WAITV6(); BAR();

  for (int i = 0; i < ni; ++i) {
    const int j = 2 * i;
    const bool full = (i + 1 < ni);
    // ph1 (d0, qa0, b0): 12 reads; stage d1.A1(j+1)
    RDA(0, 0); RDB(0, 0, b0); STG(0, 1, 1, j + 1);
    BAR(); LGKM0(); MM16(0, 0, b0); BAR();
    // ph2 (d0, qa0, b1): 4 reads; stage d0.A0(j+2) [d0.A0 read only ph1]
    RDB(0, 1, b1); if (full) STG(0, 0, 0, j + 2);
    BAR(); LGKM0(); MM16(0, 1, b1); BAR();
    // ph3 (d0, qa1, b0): 8 reads (b0 held from ph1); stage d0.B0(j+2)
    RDA(0, 1); if (full) STG(1, 0, 0, j + 2);
    BAR(); LGKM0(); MM16(1, 0, b0); BAR();
    // ph4 (d0, qa1, b1): 0 reads; stage d0.B1(j+2); counted wait AFTER MFMA
    if (full) STG(1, 1, 0, j + 2);
    BAR(); MM16(1, 1, b1);
    if (full) { WAITV6(); } else { WAITV0(); }
    BAR();
    // ph5 (d1, qa0, b0): 12 reads; stage d0.A1(j+2) [d0.A1 read ph3]
    RDA(1, 0); RDB(1, 0, b0); if (full) STG(0, 1, 0, j + 2);
    BAR(); LGKM0(); MM16(0, 0, b0); BAR();
    // ph6 (d1, qa0, b1): 4 reads; stage d1.A0(j+3)
    RDB(1, 1, b1); if (full) STG(0, 0, 1, j + 3);
    BAR(); LGKM0(); MM16(0, 1, b1); BAR();
    // ph7 (d1, qa1, b0): 8 reads; stage d1.B0(j+3)
    RDA(1, 1); if (full) STG(1, 0, 1, j + 3);
    BAR(); LGKM0(); MM16(1, 0, b0); BAR();
    // ph8 (d1, qa1, b1): 0 reads; stage d1.B1(j+3); counted wait
    if (full) STG(1, 1, 1, j + 3);
    BAR(); MM16(1, 1, b1);
    if (full) WAITV6();
    BAR();
  }

  if (MODE == 1) {
    // exp + bf16 store + per-row exp-sum (16-lane groups share row m).
    unsigned short* C = (unsigned short*)Cout;
#pragma unroll
    for (int qa = 0; qa < 2; ++qa)
#pragma unroll
      for (int rt = 0; rt < 4; ++rt)
#pragma unroll
        for (int reg = 0; reg < 4; ++reg) {
          const int m = m0 + qa * 128 + wrow * 64 + rt * 16 + lq * 4 + reg;
          float s = 0.f;
#pragma unroll
          for (int bh = 0; bh < 2; ++bh)
#pragma unroll
            for (int ct = 0; ct < 2; ++ct) {
              const int n = n0 + bh * 128 + wcol * 32 + ct * 16 + lr;
              float p = __expf(acc[qa][bh][rt][ct][reg]);
              C[(size_t)m * N + n] = f2bf(p);
              s += p;
            }
#pragma unroll
          for (int off = 1; off < 16; off <<= 1) s += __shfl_xor(s, off, 64);
          if (lr == 0) atomicAdd(&rowsum[m], s);
        }
  } else {
    // split-K partials: atomicAdd fp32 of acc/rowsum[m] into C.
    float* C = (float*)Cout;
#pragma unroll
    for (int qa = 0; qa < 2; ++qa)
#pragma unroll
      for (int rt = 0; rt < 4; ++rt)
#pragma unroll
        for (int reg = 0; reg < 4; ++reg) {
          const int m = m0 + qa * 128 + wrow * 64 + rt * 16 + lq * 4 + reg;
          const float inv = 1.0f / rowsum[m];
#pragma unroll
          for (int bh = 0; bh < 2; ++bh)
#pragma unroll
            for (int ct = 0; ct < 2; ++ct) {
              const int n = n0 + bh * 128 + wcol * 32 + ct * 16 + lr;
              atomicAdd(&C[(size_t)m * N + n], acc[qa][bh][rt][ct][reg] * inv);
            }
        }
  }
#undef STG
#undef RDA
#undef RDB
#undef MM16
#undef WAITV6
#undef WAITV0
#undef LGKM0
#undef BAR
}

// ---------------- 128^2 2-barrier engine (K1a/K1b; R15-measured) ----------
template <int MODE>
__launch_bounds__(256, 4)
__global__ void gemm_bt(const unsigned short* __restrict__ A,
                        const unsigned short* __restrict__ B,
                        void* __restrict__ Cout,
                        int M, int N, int K, float alpha,
                        float* __restrict__ rowsum, int kChunk,
                        const unsigned short* __restrict__ B2,
                        void* __restrict__ Cout2, float alpha2) {
  __shared__ __align__(16) unsigned short lA[128 * LROW];
  __shared__ __align__(16) unsigned short lB[128 * LROW];

  if (MODE == 0) {
    if (blockIdx.z == 1) { B = B2; Cout = Cout2; alpha = alpha2; }
  }
  const int kOff = (MODE == 2) ? blockIdx.z * kChunk : 0;

  const int t    = threadIdx.x;
  const int w    = t >> 6;
  const int l    = t & 63;
  const int r32  = l & 31;
  const int kh   = l >> 5;
  const int m0   = blockIdx.x * 128;
  const int n0   = blockIdx.y * 128;
  const int wm   = (w & 1) * 64;
  const int wn   = (w >> 1) * 64;

  int gOff[4], dOff[4];
#pragma unroll
  for (int h = 0; h < 4; ++h) {
    int c   = t + (h << 8);
    int row = c >> 3;
    int j   = c & 7;
    gOff[h] = row * K + ((j ^ (row & 7)) << 3);
    dOff[h] = c << 3;
  }
  const unsigned short* Abase = A + (size_t)m0 * K + kOff;
  const unsigned short* Bbase = B + (size_t)n0 * K + kOff;

  const int xr = (r32 & 7) << 3;
  int offA0[4], offA1[4], offB0[4], offB1[4];
#pragma unroll
  for (int ks = 0; ks < 4; ++ks) {
    const int gg = (((ks << 1) | kh) << 3) ^ xr;
    offA0[ks] = (wm      + r32) * LROW + gg;
    offA1[ks] = (wm + 32 + r32) * LROW + gg;
    offB0[ks] = (wn      + r32) * LROW + gg;
    offB1[ks] = (wn + 32 + r32) * LROW + gg;
  }

  f32x16 acc[2][2] = {};
  const int nk = kChunk >> 6;

#pragma unroll
  for (int h = 0; h < 4; ++h) gload16(Abase + gOff[h], &lA[dOff[h]]);
#pragma unroll
  for (int h = 0; h < 4; ++h) gload16(Bbase + gOff[h], &lB[dOff[h]]);
  __syncthreads();

  for (int kt = 0; kt < nk; ++kt) {
#pragma unroll
    for (int ks = 0; ks < 4; ++ks) {
      bf16x8 a0 = *(const bf16x8*)&lA[offA0[ks]];
      bf16x8 a1 = *(const bf16x8*)&lA[offA1[ks]];
      bf16x8 b0 = *(const bf16x8*)&lB[offB0[ks]];
      bf16x8 b1 = *(const bf16x8*)&lB[offB1[ks]];
      acc[0][0] = __builtin_amdgcn_mfma_f32_32x32x16_bf16(a0, b0, acc[0][0], 0, 0, 0);
      acc[0][1] = __builtin_amdgcn_mfma_f32_32x32x16_bf16(a0, b1, acc[0][1], 0, 0, 0);
      acc[1][0] = __builtin_amdgcn_mfma_f32_32x32x16_bf16(a1, b0, acc[1][0], 0, 0, 0);
      acc[1][1] = __builtin_amdgcn_mfma_f32_32x32x16_bf16(a1, b1, acc[1][1], 0, 0, 0);
    }
    if (kt + 1 < nk) {
      __syncthreads();
      const int ko = (kt + 1) << 6;
#pragma unroll
      for (int h = 0; h < 4; ++h) gload16(Abase + gOff[h] + ko, &lA[dOff[h]]);
#pragma unroll
      for (int h = 0; h < 4; ++h) gload16(Bbase + gOff[h] + ko, &lB[dOff[h]]);
      __syncthreads();
    }
  }

  if (MODE == 0) {
    unsigned short* C = (unsigned short*)Cout;
#pragma unroll
    for (int mi = 0; mi < 2; ++mi)
#pragma unroll
      for (int reg = 0; reg < 16; ++reg) {
        int m = m0 + wm + mi * 32 + (reg & 3) + ((reg >> 2) << 3) + (kh << 2);
#pragma unroll
        for (int ni = 0; ni < 2; ++ni) {
          int n = n0 + wn + ni * 32 + r32;
          C[(size_t)m * N + n] = f2bf(acc[mi][ni][reg] * alpha);
        }
      }
  } else if (MODE == 2) {
    float* C = (float*)Cout;
#pragma unroll
    for (int mi = 0; mi < 2; ++mi)
#pragma unroll
      for (int reg = 0; reg < 16; ++reg) {
        int m = m0 + wm + mi * 32 + (reg & 3) + ((reg >> 2) << 3) + (kh << 2);
        float inv = 1.0f / rowsum[m];
#pragma unroll
        for (int ni = 0; ni < 2; ++ni) {
          int n = n0 + wn + ni * 32 + r32;
          atomicAdd(&C[(size_t)m * N + n], acc[mi][ni][reg] * inv);
        }
      }
  }
}

extern "C" void kernel_launch(void* const* d_in, const int* in_sizes, int n_in,
                              void* d_out, int out_size, void* d_ws, size_t ws_size,
                              hipStream_t stream) {
  const float* x  = (const float*)d_in[0];
  const float* Wq = (const float*)d_in[1];
  const float* Wk = (const float*)d_in[2];
  const float* Wv = (const float*)d_in[3];

  char* ws = (char*)d_ws;
  unsigned short* xb     = (unsigned short*)(ws + 0);
  unsigned short* Qb     = (unsigned short*)(ws + 12582912);
  unsigned short* Kb     = (unsigned short*)(ws + 25165824);
  unsigned short* Vtb    = (unsigned short*)(ws + 37748736);
  unsigned short* wqb    = (unsigned short*)(ws + 50331648);
  unsigned short* wkb    = (unsigned short*)(ws + 51511296);
  unsigned short* wvb    = (unsigned short*)(ws + 52690944);
  float*          rowsum = (float*)(ws + 53870592);
  unsigned short* Pb     = (unsigned short*)(ws + 53903360);
  const size_t need = 53903360u + (size_t)SEQ * SEQ * 2u;
  if (ws_size < need) return;

  hipMemsetAsync(rowsum, 0, SEQ * sizeof(float), stream);
  hipMemsetAsync(d_out, 0, (size_t)out_size * sizeof(float), stream);

  convert_x<<<SEQ * DMODEL / 1024, 256, 0, stream>>>(x, xb, SEQ * DMODEL / 4);
  convert_w<<<dim3(DMODEL * DMODEL / 1024, 1, 3), 256, 0, stream>>>(
      Wq, Wk, Wv, wqb, wkb, wvb, DMODEL * DMODEL / 4);

  const float alpha_q = 0.03608439182435161f;  // 1/sqrt(768)
  // K1a/K1b on the 128^2 engine (768 / 384 blocks)
  gemm_bt<0><<<dim3(SEQ / 128, DMODEL / 128, 2), dim3(256), 0, stream>>>(
      xb, wqb, Qb, SEQ, DMODEL, DMODEL, alpha_q, nullptr, DMODEL,
      wkb, Kb, 1.0f);
  gemm_bt<0><<<dim3(DMODEL / 128, SEQ / 128, 1), dim3(256), 0, stream>>>(
      wvb, xb, Vtb, DMODEL, SEQ, DMODEL, 1.0f, nullptr, DMODEL,
      nullptr, nullptr, 1.0f);
  // K2: 256^2 8-phase, exp + rowsum (1024 blocks)
  gemm256<1><<<dim3(SEQ / 256, SEQ / 256), dim3(512), 0, stream>>>(
      Qb, Kb, Pb, SEQ, DMODEL, rowsum, DMODEL);
  // K3: 256^2 8-phase, split-K x8 (32 x 3 x 8 = 768 blocks = 3/CU balanced)
  gemm256<2><<<dim3(SEQ / 256, DMODEL / 256, KSPLIT), dim3(512), 0, stream>>>(
      Pb, Vtb, d_out, DMODEL, SEQ, rowsum, SEQ / KSPLIT);
}

// Round 9
// 406.315 us; speedup vs baseline: 1.1490x; 1.1490x over previous
//
#include <hip/hip_runtime.h>
#include <stdint.h>

// Self-attention, SEQ=8192, D=768, single head.
//   K0a: x fp32->bf16; K0b: Wq/Wk/Wv fp32->bf16 (z-fused)
//   K1a: Q,K projections z-fused (128^2 engine, MODE 0)
//   K1b: Vt = Wv x^T (128^2, MODE 0)
//   K2 : P' = exp(Q K^T) bf16 + rowsums     (256^2 8-phase engine)
//   K3 : out += (P' V)/rowsum, split-K x4   (128^2 engine, MODE 2)
//
// R19 = exact R17 restore (best measured: 392 us). R18 post-mortem:
// K3 on the 256^2 engine REGRESSED 157->230 us. Counters: WRITE 202 MB
// (8x25 MB fp32 atomics), FETCH 134 MB (P read once), MfmaUtil 18%.
// Diagnosis: 128 KB LDS -> 1 block/CU -> 768 blocks = 3 serial rounds;
// each round's epilogue (32 fp32 atomicAdds/thread, 8-way inter-block
// contention on the same lines, cross-XCD RMW) + prologue is UNHIDDEN
// (~35 us/round). A=P row stride 16 KB also worsens stage latency vs
// K2's 1.5 KB. RULE: the 256^2 8-phase engine only pays off when the
// epilogue is cheap streaming stores and rounds are few (K2); atomic
// split-K epilogues stay on the 4-resident 128^2 engine (K3).
// This round also surfaces gemm256<1> (K2) counters in top-5 for the
// first time (previously inferred by subtraction) to pick the next lever.

#define SEQ    8192
#define DMODEL 768
#define KSPLIT 4             // split-K for K3 (128^2 engine)
#define LROW   64            // 128^2 engine LDS row stride (halfwords)

typedef short bf16x8 __attribute__((ext_vector_type(8)));
typedef float f32x4  __attribute__((ext_vector_type(4)));
typedef float f32x16 __attribute__((ext_vector_type(16)));

__device__ __forceinline__ unsigned short f2bf(float f) {
  union { float f; unsigned int u; } v; v.f = f;
  unsigned int u = v.u;
  u += 0x7FFFu + ((u >> 16) & 1u);   // round-to-nearest-even
  return (unsigned short)(u >> 16);
}

// global -> LDS direct DMA, 16 B/lane; LDS dest wave-uniform + lane*16 (m104).
__device__ __forceinline__ void gload16(const unsigned short* g, unsigned short* l) {
  __builtin_amdgcn_global_load_lds(
      (const __attribute__((address_space(1))) unsigned int*)g,
      (__attribute__((address_space(3))) unsigned int*)l, 16, 0, 0);
}

// Stage one half-tile (128x64 bf16 = 16 KB): 512 thr x 2 x 16 B.
// LDS linear; source column pre-swizzled (slot j <- col j^(row&7)).
__device__ __forceinline__ void stage_ht(const unsigned short* __restrict__ g,
                                         int Kd, unsigned short* l, int t) {
  const int c0 = t, c1 = t + 512;
  const int r0 = c0 >> 3, r1 = c1 >> 3;
  const int s0 = ((c0 & 7) ^ (r0 & 7)) << 3;
  const int s1 = ((c1 & 7) ^ (r1 & 7)) << 3;
  gload16(g + (size_t)r0 * Kd + s0, l + (c0 << 3));
  gload16(g + (size_t)r1 * Kd + s1, l + (c1 << 3));
}

__global__ void convert_x(const float* __restrict__ src,
                          unsigned short* __restrict__ dst, int n4) {
  int i = blockIdx.x * blockDim.x + threadIdx.x;
  if (i >= n4) return;
  const float4 f = ((const float4*)src)[i];
  ushort4 o;
  o.x = f2bf(f.x); o.y = f2bf(f.y); o.z = f2bf(f.z); o.w = f2bf(f.w);
  ((ushort4*)dst)[i] = o;
}

__global__ void convert_w(const float* __restrict__ s0, const float* __restrict__ s1,
                          const float* __restrict__ s2,
                          unsigned short* __restrict__ d0, unsigned short* __restrict__ d1,
                          unsigned short* __restrict__ d2, int n4) {
  const float* s = (blockIdx.z == 0) ? s0 : (blockIdx.z == 1) ? s1 : s2;
  unsigned short* d = (blockIdx.z == 0) ? d0 : (blockIdx.z == 1) ? d1 : d2;
  int i = blockIdx.x * blockDim.x + threadIdx.x;
  if (i >= n4) return;
  const float4 f = ((const float4*)s)[i];
  ushort4 o;
  o.x = f2bf(f.x); o.y = f2bf(f.y); o.z = f2bf(f.z); o.w = f2bf(f.w);
  ((ushort4*)d)[i] = o;
}

// ---------------- 256^2 8-phase engine (K2) ----------------
// C[m,n]=sum_k A[m,k]B[n,k]; writes exp(C) bf16 + atomic rowsums.
// 8 waves (2M x 4N); per-wave out = rows {qa*128+wrow*64+0..63} x cols
// {bh*128+wcol*32+0..31}. MFMA 16x16x32: A/B frag lane row=l&15,
// k=(l>>4)*8+j; C/D col=l&15, row=(l>>4)*4+reg [m89/m91].
// LDS halfwords: [dbuf2][tensor2][half2][128][64]=65536 (128 KB).
// Schedule (verified R17: K2 164->129 us): phases (qa, b-half) per K-tile,
// reads-once-into-regs, one 16KB stage/phase, vmcnt(6) only at ph4/ph8.
__launch_bounds__(512, 2)
__global__ void gemm256_exp(const unsigned short* __restrict__ A,
                            const unsigned short* __restrict__ B,
                            unsigned short* __restrict__ C,
                            int N, int K, float* __restrict__ rowsum) {
  __shared__ __align__(16) unsigned short lds[65536];
  const int t    = threadIdx.x;
  const int w    = t >> 6, l = t & 63;
  const int lr   = l & 15, lq = l >> 4;
  const int wrow = w >> 2, wcol = w & 3;
  const int m0   = blockIdx.x * 256;
  const int n0   = blockIdx.y * 256;
  const unsigned short* Ab = A + (size_t)m0 * K;
  const unsigned short* Bb = B + (size_t)n0 * K;

  const int rA64 = (wrow * 64 + lr) * 64;
  const int rB64 = (wcol * 32 + lr) * 64;
  const int x7   = lr & 7;
  const int csw0 = ((0 + lq) ^ x7) << 3;   // ks=0 chunk
  const int csw1 = ((4 + lq) ^ x7) << 3;   // ks=1 chunk

  f32x4 acc[2][2][4][2] = {};              // [qa][bh][rt][ct]
  const int nt = K >> 6, ni = nt >> 1;

#define STG(T, H, D, JT) stage_ht(((T) ? Bb : Ab) + (size_t)((H) * 128) * K + (JT) * 64, K, \
                                  &lds[(D) * 32768 + (T) * 16384 + (H) * 8192], t)
#define RDA(D, QA) do { \
    _Pragma("unroll") for (int rt = 0; rt < 4; ++rt) { \
      a[rt][0] = *(const bf16x8*)&lds[(D)*32768 + (QA)*8192 + rA64 + rt*1024 + csw0]; \
      a[rt][1] = *(const bf16x8*)&lds[(D)*32768 + (QA)*8192 + rA64 + rt*1024 + csw1]; \
    } } while (0)
#define RDB(D, BH, DST) do { \
    _Pragma("unroll") for (int ct = 0; ct < 2; ++ct) { \
      DST[ct][0] = *(const bf16x8*)&lds[(D)*32768 + 16384 + (BH)*8192 + rB64 + ct*1024 + csw0]; \
      DST[ct][1] = *(const bf16x8*)&lds[(D)*32768 + 16384 + (BH)*8192 + rB64 + ct*1024 + csw1]; \
    } } while (0)
#define MM16(QA, BH, BR) do { \
    __builtin_amdgcn_s_setprio(1); \
    _Pragma("unroll") for (int ks = 0; ks < 2; ++ks) \
      _Pragma("unroll") for (int rt = 0; rt < 4; ++rt) \
        _Pragma("unroll") for (int ct = 0; ct < 2; ++ct) \
          acc[QA][BH][rt][ct] = __builtin_amdgcn_mfma_f32_16x16x32_bf16( \
              a[rt][ks], BR[ct][ks], acc[QA][BH][rt][ct], 0, 0, 0); \
    __builtin_amdgcn_s_setprio(0); \
  } while (0)
#define WAITV6() asm volatile("s_waitcnt vmcnt(6)" ::: "memory")
#define WAITV0() asm volatile("s_waitcnt vmcnt(0)" ::: "memory")
#define LGKM0()  asm volatile("s_waitcnt lgkmcnt(0)" ::: "memory")
#define BAR()    __builtin_amdgcn_s_barrier()

  bf16x8 a[4][2], b0[2][2], b1[2][2];

  // Prologue: tile0 (A0,B0,B1,A1)->d0, tile1 (A0,B0,B1)->d1; drain to 3.
  STG(0, 0, 0, 0); STG(1, 0, 0, 0); STG(1, 1, 0, 0); STG(0, 1, 0, 0);
  STG(0, 0, 1, 1); STG(1, 0, 1, 1); STG(1, 1, 1, 1);
  WAITV6(); BAR();

  for (int i = 0; i < ni; ++i) {
    const int j = 2 * i;
    const bool full = (i + 1 < ni);
    // ph1 (d0, qa0, b0): 12 reads; stage d1.A1(j+1)
    RDA(0, 0); RDB(0, 0, b0); STG(0, 1, 1, j + 1);
    BAR(); LGKM0(); MM16(0, 0, b0); BAR();
    // ph2 (d0, qa0, b1): 4 reads; stage d0.A0(j+2)
    RDB(0, 1, b1); if (full) STG(0, 0, 0, j + 2);
    BAR(); LGKM0(); MM16(0, 1, b1); BAR();
    // ph3 (d0, qa1, b0): 8 reads; stage d0.B0(j+2)
    RDA(0, 1); if (full) STG(1, 0, 0, j + 2);
    BAR(); LGKM0(); MM16(1, 0, b0); BAR();
    // ph4 (d0, qa1, b1): 0 reads; stage d0.B1(j+2); counted wait AFTER MFMA
    if (full) STG(1, 1, 0, j + 2);
    BAR(); MM16(1, 1, b1);
    if (full) { WAITV6(); } else { WAITV0(); }
    BAR();
    // ph5 (d1, qa0, b0): 12 reads; stage d0.A1(j+2)
    RDA(1, 0); RDB(1, 0, b0); if (full) STG(0, 1, 0, j + 2);
    BAR(); LGKM0(); MM16(0, 0, b0); BAR();
    // ph6 (d1, qa0, b1): 4 reads; stage d1.A0(j+3)
    RDB(1, 1, b1); if (full) STG(0, 0, 1, j + 3);
    BAR(); LGKM0(); MM16(0, 1, b1); BAR();
    // ph7 (d1, qa1, b0): 8 reads; stage d1.B0(j+3)
    RDA(1, 1); if (full) STG(1, 0, 1, j + 3);
    BAR(); LGKM0(); MM16(1, 0, b0); BAR();
    // ph8 (d1, qa1, b1): 0 reads; stage d1.B1(j+3); counted wait
    if (full) STG(1, 1, 1, j + 3);
    BAR(); MM16(1, 1, b1);
    if (full) WAITV6();
    BAR();
  }

  // Epilogue: exp + bf16 store + per-row exp-sum (16-lane groups share m).
#pragma unroll
  for (int qa = 0; qa < 2; ++qa)
#pragma unroll
    for (int rt = 0; rt < 4; ++rt)
#pragma unroll
      for (int reg = 0; reg < 4; ++reg) {
        const int m = m0 + qa * 128 + wrow * 64 + rt * 16 + lq * 4 + reg;
        float s = 0.f;
#pragma unroll
        for (int bh = 0; bh < 2; ++bh)
#pragma unroll
          for (int ct = 0; ct < 2; ++ct) {
            const int n = n0 + bh * 128 + wcol * 32 + ct * 16 + lr;
            float p = __expf(acc[qa][bh][rt][ct][reg]);
            C[(size_t)m * N + n] = f2bf(p);
            s += p;
          }
#pragma unroll
        for (int off = 1; off < 16; off <<= 1) s += __shfl_xor(s, off, 64);
        if (lr == 0) atomicAdd(&rowsum[m], s);
      }
#undef STG
#undef RDA
#undef RDB
#undef MM16
#undef WAITV6
#undef WAITV0
#undef LGKM0
#undef BAR
}

// ---------------- 128^2 2-barrier engine (K1a/K1b/K3; R15/R17-measured) ----
template <int MODE>
__launch_bounds__(256, 4)
__global__ void gemm_bt(const unsigned short* __restrict__ A,
                        const unsigned short* __restrict__ B,
                        void* __restrict__ Cout,
                        int M, int N, int K, float alpha,
                        float* __restrict__ rowsum, int kChunk,
                        const unsigned short* __restrict__ B2,
                        void* __restrict__ Cout2, float alpha2) {
  __shared__ __align__(16) unsigned short lA[128 * LROW];
  __shared__ __align__(16) unsigned short lB[128 * LROW];

  if (MODE == 0) {
    if (blockIdx.z == 1) { B = B2; Cout = Cout2; alpha = alpha2; }
  }
  const int kOff = (MODE == 2) ? blockIdx.z * kChunk : 0;

  const int t    = threadIdx.x;
  const int w    = t >> 6;
  const int l    = t & 63;
  const int r32  = l & 31;
  const int kh   = l >> 5;
  const int m0   = blockIdx.x * 128;
  const int n0   = blockIdx.y * 128;
  const int wm   = (w & 1) * 64;
  const int wn   = (w >> 1) * 64;

  int gOff[4], dOff[4];
#pragma unroll
  for (int h = 0; h < 4; ++h) {
    int c   = t + (h << 8);
    int row = c >> 3;
    int j   = c & 7;
    gOff[h] = row * K + ((j ^ (row & 7)) << 3);
    dOff[h] = c << 3;
  }
  const unsigned short* Abase = A + (size_t)m0 * K + kOff;
  const unsigned short* Bbase = B + (size_t)n0 * K + kOff;

  const int xr = (r32 & 7) << 3;
  int offA0[4], offA1[4], offB0[4], offB1[4];
#pragma unroll
  for (int ks = 0; ks < 4; ++ks) {
    const int gg = (((ks << 1) | kh) << 3) ^ xr;
    offA0[ks] = (wm      + r32) * LROW + gg;
    offA1[ks] = (wm + 32 + r32) * LROW + gg;
    offB0[ks] = (wn      + r32) * LROW + gg;
    offB1[ks] = (wn + 32 + r32) * LROW + gg;
  }

  f32x16 acc[2][2] = {};
  const int nk = kChunk >> 6;

#pragma unroll
  for (int h = 0; h < 4; ++h) gload16(Abase + gOff[h], &lA[dOff[h]]);
#pragma unroll
  for (int h = 0; h < 4; ++h) gload16(Bbase + gOff[h], &lB[dOff[h]]);
  __syncthreads();

  for (int kt = 0; kt < nk; ++kt) {
#pragma unroll
    for (int ks = 0; ks < 4; ++ks) {
      bf16x8 a0 = *(const bf16x8*)&lA[offA0[ks]];
      bf16x8 a1 = *(const bf16x8*)&lA[offA1[ks]];
      bf16x8 b0 = *(const bf16x8*)&lB[offB0[ks]];
      bf16x8 b1 = *(const bf16x8*)&lB[offB1[ks]];
      acc[0][0] = __builtin_amdgcn_mfma_f32_32x32x16_bf16(a0, b0, acc[0][0], 0, 0, 0);
      acc[0][1] = __builtin_amdgcn_mfma_f32_32x32x16_bf16(a0, b1, acc[0][1], 0, 0, 0);
      acc[1][0] = __builtin_amdgcn_mfma_f32_32x32x16_bf16(a1, b0, acc[1][0], 0, 0, 0);
      acc[1][1] = __builtin_amdgcn_mfma_f32_32x32x16_bf16(a1, b1, acc[1][1], 0, 0, 0);
    }
    if (kt + 1 < nk) {
      __syncthreads();
      const int ko = (kt + 1) << 6;
#pragma unroll
      for (int h = 0; h < 4; ++h) gload16(Abase + gOff[h] + ko, &lA[dOff[h]]);
#pragma unroll
      for (int h = 0; h < 4; ++h) gload16(Bbase + gOff[h] + ko, &lB[dOff[h]]);
      __syncthreads();
    }
  }

  if (MODE == 0) {
    unsigned short* C = (unsigned short*)Cout;
#pragma unroll
    for (int mi = 0; mi < 2; ++mi)
#pragma unroll
      for (int reg = 0; reg < 16; ++reg) {
        int m = m0 + wm + mi * 32 + (reg & 3) + ((reg >> 2) << 3) + (kh << 2);
#pragma unroll
        for (int ni = 0; ni < 2; ++ni) {
          int n = n0 + wn + ni * 32 + r32;
          C[(size_t)m * N + n] = f2bf(acc[mi][ni][reg] * alpha);
        }
      }
  } else if (MODE == 2) {
    float* C = (float*)Cout;
#pragma unroll
    for (int mi = 0; mi < 2; ++mi)
#pragma unroll
      for (int reg = 0; reg < 16; ++reg) {
        int m = m0 + wm + mi * 32 + (reg & 3) + ((reg >> 2) << 3) + (kh << 2);
        float inv = 1.0f / rowsum[m];
#pragma unroll
        for (int ni = 0; ni < 2; ++ni) {
          int n = n0 + wn + ni * 32 + r32;
          atomicAdd(&C[(size_t)m * N + n], acc[mi][ni][reg] * inv);
        }
      }
  }
}

extern "C" void kernel_launch(void* const* d_in, const int* in_sizes, int n_in,
                              void* d_out, int out_size, void* d_ws, size_t ws_size,
                              hipStream_t stream) {
  const float* x  = (const float*)d_in[0];
  const float* Wq = (const float*)d_in[1];
  const float* Wk = (const float*)d_in[2];
  const float* Wv = (const float*)d_in[3];

  char* ws = (char*)d_ws;
  unsigned short* xb     = (unsigned short*)(ws + 0);
  unsigned short* Qb     = (unsigned short*)(ws + 12582912);
  unsigned short* Kb     = (unsigned short*)(ws + 25165824);
  unsigned short* Vtb    = (unsigned short*)(ws + 37748736);
  unsigned short* wqb    = (unsigned short*)(ws + 50331648);
  unsigned short* wkb    = (unsigned short*)(ws + 51511296);
  unsigned short* wvb    = (unsigned short*)(ws + 52690944);
  float*          rowsum = (float*)(ws + 53870592);
  unsigned short* Pb     = (unsigned short*)(ws + 53903360);
  const size_t need = 53903360u + (size_t)SEQ * SEQ * 2u;
  if (ws_size < need) return;

  hipMemsetAsync(rowsum, 0, SEQ * sizeof(float), stream);
  hipMemsetAsync(d_out, 0, (size_t)out_size * sizeof(float), stream);

  convert_x<<<SEQ * DMODEL / 1024, 256, 0, stream>>>(x, xb, SEQ * DMODEL / 4);
  convert_w<<<dim3(DMODEL * DMODEL / 1024, 1, 3), 256, 0, stream>>>(
      Wq, Wk, Wv, wqb, wkb, wvb, DMODEL * DMODEL / 4);

  const float alpha_q = 0.03608439182435161f;  // 1/sqrt(768)
  // K1a/K1b on the 128^2 engine (768 / 384 blocks)
  gemm_bt<0><<<dim3(SEQ / 128, DMODEL / 128, 2), dim3(256), 0, stream>>>(
      xb, wqb, Qb, SEQ, DMODEL, DMODEL, alpha_q, nullptr, DMODEL,
      wkb, Kb, 1.0f);
  gemm_bt<0><<<dim3(DMODEL / 128, SEQ / 128, 1), dim3(256), 0, stream>>>(
      wvb, xb, Vtb, DMODEL, SEQ, DMODEL, 1.0f, nullptr, DMODEL,
      nullptr, nullptr, 1.0f);
  // K2: 256^2 8-phase, exp + rowsum (1024 blocks)
  gemm256_exp<<<dim3(SEQ / 256, SEQ / 256), dim3(512), 0, stream>>>(
      Qb, Kb, Pb, SEQ, DMODEL, rowsum);
  // K3: 128^2 engine, split-K x4 (64 x 6 x 4 = 1536 blocks, 4-resident)
  gemm_bt<2><<<dim3(SEQ / 128, DMODEL / 128, KSPLIT), dim3(256), 0, stream>>>(
      Pb, Vtb, d_out, SEQ, DMODEL, SEQ, 1.0f, rowsum, SEQ / KSPLIT,
      nullptr, nullptr, 1.0f);
}

// Round 10
// 396.434 us; speedup vs baseline: 1.1776x; 1.0249x over previous
//
#include <hip/hip_runtime.h>
#include <stdint.h>

// Self-attention, SEQ=8192, D=768, single head.
//   K0 : fused convert x/Wq/Wk/Wv fp32->bf16 (one launch)
//   K1 : fused Q,K,Vt projections, z=3 (128^2 engine, MODE 0)   <- R20
//   K2 : P' = exp(Q K^T) bf16 + rowsums     (256^2 8-phase engine)
//   K3 : out += (P' V)/rowsum, split-K x4   (128^2 engine, MODE 2)
//
// R20: launch fusion on measured-good engines (no schedule changes).
// R19 budget: K3=157, K2~129, rest ~120 us. K1b standalone = 384 blocks
// = 1.5/CU (machine >half idle); 6 launches x ~5-10 us gaps. Fix: all
// three projections share K=768 and identical staging -> one z=3 dispatch
// (grid 64x6x3 = 1152 blocks; z==2 swaps bx/by and uses N=8192 for Vt).
// Converts merged into one range-decoded kernel.
// Session noise note: R17 and R19 are identical code, 392 vs 406 us ->
// cross-session noise +-3-4%; judge this round by the fused dispatch's
// own dur_us, not total alone.

#define SEQ    8192
#define DMODEL 768
#define KSPLIT 4             // split-K for K3 (128^2 engine)
#define LROW   64            // 128^2 engine LDS row stride (halfwords)

typedef short bf16x8 __attribute__((ext_vector_type(8)));
typedef float f32x4  __attribute__((ext_vector_type(4)));
typedef float f32x16 __attribute__((ext_vector_type(16)));

__device__ __forceinline__ unsigned short f2bf(float f) {
  union { float f; unsigned int u; } v; v.f = f;
  unsigned int u = v.u;
  u += 0x7FFFu + ((u >> 16) & 1u);   // round-to-nearest-even
  return (unsigned short)(u >> 16);
}

// global -> LDS direct DMA, 16 B/lane; LDS dest wave-uniform + lane*16 (m104).
__device__ __forceinline__ void gload16(const unsigned short* g, unsigned short* l) {
  __builtin_amdgcn_global_load_lds(
      (const __attribute__((address_space(1))) unsigned int*)g,
      (__attribute__((address_space(3))) unsigned int*)l, 16, 0, 0);
}

// Stage one half-tile (128x64 bf16 = 16 KB): 512 thr x 2 x 16 B.
// LDS linear; source column pre-swizzled (slot j <- col j^(row&7)).
__device__ __forceinline__ void stage_ht(const unsigned short* __restrict__ g,
                                         int Kd, unsigned short* l, int t) {
  const int c0 = t, c1 = t + 512;
  const int r0 = c0 >> 3, r1 = c1 >> 3;
  const int s0 = ((c0 & 7) ^ (r0 & 7)) << 3;
  const int s1 = ((c1 & 7) ^ (r1 & 7)) << 3;
  gload16(g + (size_t)r0 * Kd + s0, l + (c0 << 3));
  gload16(g + (size_t)r1 * Kd + s1, l + (c1 << 3));
}

// K0: all four fp32->bf16 converts in one launch, range-decoded.
__global__ void convert_all(const float* __restrict__ x,  const float* __restrict__ Wq,
                            const float* __restrict__ Wk, const float* __restrict__ Wv,
                            unsigned short* __restrict__ xb,  unsigned short* __restrict__ wqb,
                            unsigned short* __restrict__ wkb, unsigned short* __restrict__ wvb) {
  const int NX = SEQ * DMODEL / 4;        // float4 count for x
  const int NW = DMODEL * DMODEL / 4;     // per weight
  int i = blockIdx.x * blockDim.x + threadIdx.x;
  const float* s; unsigned short* d; int off;
  if (i < NX)                { s = x;  d = xb;  off = i; }
  else if (i < NX + NW)      { s = Wq; d = wqb; off = i - NX; }
  else if (i < NX + 2 * NW)  { s = Wk; d = wkb; off = i - NX - NW; }
  else if (i < NX + 3 * NW)  { s = Wv; d = wvb; off = i - NX - 2 * NW; }
  else return;
  const float4 f = ((const float4*)s)[off];
  ushort4 o;
  o.x = f2bf(f.x); o.y = f2bf(f.y); o.z = f2bf(f.z); o.w = f2bf(f.w);
  ((ushort4*)d)[off] = o;
}

// ---------------- 256^2 8-phase engine (K2) ----------------
// C[m,n]=sum_k A[m,k]B[n,k]; writes exp(C) bf16 + atomic rowsums.
// 8 waves (2M x 4N); MFMA 16x16x32: A/B frag lane row=l&15, k=(l>>4)*8+j;
// C/D col=l&15, row=(l>>4)*4+reg [m89/m91].
// LDS halfwords: [dbuf2][tensor2][half2][128][64]=65536 (128 KB).
// Schedule (verified R17: K2 164->129 us): phases (qa, b-half) per K-tile,
// reads-once-into-regs, one 16KB stage/phase, vmcnt(6) only at ph4/ph8.
__launch_bounds__(512, 2)
__global__ void gemm256_exp(const unsigned short* __restrict__ A,
                            const unsigned short* __restrict__ B,
                            unsigned short* __restrict__ C,
                            int N, int K, float* __restrict__ rowsum) {
  __shared__ __align__(16) unsigned short lds[65536];
  const int t    = threadIdx.x;
  const int w    = t >> 6, l = t & 63;
  const int lr   = l & 15, lq = l >> 4;
  const int wrow = w >> 2, wcol = w & 3;
  const int m0   = blockIdx.x * 256;
  const int n0   = blockIdx.y * 256;
  const unsigned short* Ab = A + (size_t)m0 * K;
  const unsigned short* Bb = B + (size_t)n0 * K;

  const int rA64 = (wrow * 64 + lr) * 64;
  const int rB64 = (wcol * 32 + lr) * 64;
  const int x7   = lr & 7;
  const int csw0 = ((0 + lq) ^ x7) << 3;   // ks=0 chunk
  const int csw1 = ((4 + lq) ^ x7) << 3;   // ks=1 chunk

  f32x4 acc[2][2][4][2] = {};              // [qa][bh][rt][ct]
  const int nt = K >> 6, ni = nt >> 1;

#define STG(T, H, D, JT) stage_ht(((T) ? Bb : Ab) + (size_t)((H) * 128) * K + (JT) * 64, K, \
                                  &lds[(D) * 32768 + (T) * 16384 + (H) * 8192], t)
#define RDA(D, QA) do { \
    _Pragma("unroll") for (int rt = 0; rt < 4; ++rt) { \
      a[rt][0] = *(const bf16x8*)&lds[(D)*32768 + (QA)*8192 + rA64 + rt*1024 + csw0]; \
      a[rt][1] = *(const bf16x8*)&lds[(D)*32768 + (QA)*8192 + rA64 + rt*1024 + csw1]; \
    } } while (0)
#define RDB(D, BH, DST) do { \
    _Pragma("unroll") for (int ct = 0; ct < 2; ++ct) { \
      DST[ct][0] = *(const bf16x8*)&lds[(D)*32768 + 16384 + (BH)*8192 + rB64 + ct*1024 + csw0]; \
      DST[ct][1] = *(const bf16x8*)&lds[(D)*32768 + 16384 + (BH)*8192 + rB64 + ct*1024 + csw1]; \
    } } while (0)
#define MM16(QA, BH, BR) do { \
    __builtin_amdgcn_s_setprio(1); \
    _Pragma("unroll") for (int ks = 0; ks < 2; ++ks) \
      _Pragma("unroll") for (int rt = 0; rt < 4; ++rt) \
        _Pragma("unroll") for (int ct = 0; ct < 2; ++ct) \
          acc[QA][BH][rt][ct] = __builtin_amdgcn_mfma_f32_16x16x32_bf16( \
              a[rt][ks], BR[ct][ks], acc[QA][BH][rt][ct], 0, 0, 0); \
    __builtin_amdgcn_s_setprio(0); \
  } while (0)
#define WAITV6() asm volatile("s_waitcnt vmcnt(6)" ::: "memory")
#define WAITV0() asm volatile("s_waitcnt vmcnt(0)" ::: "memory")
#define LGKM0()  asm volatile("s_waitcnt lgkmcnt(0)" ::: "memory")
#define BAR()    __builtin_amdgcn_s_barrier()

  bf16x8 a[4][2], b0[2][2], b1[2][2];

  // Prologue: tile0 (A0,B0,B1,A1)->d0, tile1 (A0,B0,B1)->d1; drain to 3.
  STG(0, 0, 0, 0); STG(1, 0, 0, 0); STG(1, 1, 0, 0); STG(0, 1, 0, 0);
  STG(0, 0, 1, 1); STG(1, 0, 1, 1); STG(1, 1, 1, 1);
  WAITV6(); BAR();

  for (int i = 0; i < ni; ++i) {
    const int j = 2 * i;
    const bool full = (i + 1 < ni);
    // ph1 (d0, qa0, b0): 12 reads; stage d1.A1(j+1)
    RDA(0, 0); RDB(0, 0, b0); STG(0, 1, 1, j + 1);
    BAR(); LGKM0(); MM16(0, 0, b0); BAR();
    // ph2 (d0, qa0, b1): 4 reads; stage d0.A0(j+2)
    RDB(0, 1, b1); if (full) STG(0, 0, 0, j + 2);
    BAR(); LGKM0(); MM16(0, 1, b1); BAR();
    // ph3 (d0, qa1, b0): 8 reads; stage d0.B0(j+2)
    RDA(0, 1); if (full) STG(1, 0, 0, j + 2);
    BAR(); LGKM0(); MM16(1, 0, b0); BAR();
    // ph4 (d0, qa1, b1): 0 reads; stage d0.B1(j+2); counted wait AFTER MFMA
    if (full) STG(1, 1, 0, j + 2);
    BAR(); MM16(1, 1, b1);
    if (full) { WAITV6(); } else { WAITV0(); }
    BAR();
    // ph5 (d1, qa0, b0): 12 reads; stage d0.A1(j+2)
    RDA(1, 0); RDB(1, 0, b0); if (full) STG(0, 1, 0, j + 2);
    BAR(); LGKM0(); MM16(0, 0, b0); BAR();
    // ph6 (d1, qa0, b1): 4 reads; stage d1.A0(j+3)
    RDB(1, 1, b1); if (full) STG(0, 0, 1, j + 3);
    BAR(); LGKM0(); MM16(0, 1, b1); BAR();
    // ph7 (d1, qa1, b0): 8 reads; stage d1.B0(j+3)
    RDA(1, 1); if (full) STG(1, 0, 1, j + 3);
    BAR(); LGKM0(); MM16(1, 0, b0); BAR();
    // ph8 (d1, qa1, b1): 0 reads; stage d1.B1(j+3); counted wait
    if (full) STG(1, 1, 1, j + 3);
    BAR(); MM16(1, 1, b1);
    if (full) WAITV6();
    BAR();
  }

  // Epilogue: exp + bf16 store + per-row exp-sum (16-lane groups share m).
#pragma unroll
  for (int qa = 0; qa < 2; ++qa)
#pragma unroll
    for (int rt = 0; rt < 4; ++rt)
#pragma unroll
      for (int reg = 0; reg < 4; ++reg) {
        const int m = m0 + qa * 128 + wrow * 64 + rt * 16 + lq * 4 + reg;
        float s = 0.f;
#pragma unroll
        for (int bh = 0; bh < 2; ++bh)
#pragma unroll
          for (int ct = 0; ct < 2; ++ct) {
            const int n = n0 + bh * 128 + wcol * 32 + ct * 16 + lr;
            float p = __expf(acc[qa][bh][rt][ct][reg]);
            C[(size_t)m * N + n] = f2bf(p);
            s += p;
          }
#pragma unroll
        for (int off = 1; off < 16; off <<= 1) s += __shfl_xor(s, off, 64);
        if (lr == 0) atomicAdd(&rowsum[m], s);
      }
#undef STG
#undef RDA
#undef RDB
#undef MM16
#undef WAITV6
#undef WAITV0
#undef LGKM0
#undef BAR
}

// ---------------- 128^2 2-barrier engine (K1 fused / K3) ----------------
// MODE 0 (fused QKV projections, all K=768):
//   z=0: C = A·B^T       (Q = x Wq^T, alpha=1/sqrt(768), N=768)
//   z=1: C = A·B2^T      (K = x Wk^T, alpha=1, N=768)
//   z=2: C = A3·A^T      (Vt = Wv x^T, alpha=1, N=8192; bx/by swapped)
// MODE 2: split-K over z (kChunk each); atomicAdd fp32 C/rowsum[m] into Cout
template <int MODE>
__launch_bounds__(256, 4)
__global__ void gemm_bt(const unsigned short* __restrict__ A,
                        const unsigned short* __restrict__ B,
                        void* __restrict__ Cout,
                        int M, int N, int K, float alpha,
                        float* __restrict__ rowsum, int kChunk,
                        const unsigned short* __restrict__ B2,
                        void* __restrict__ Cout2, float alpha2,
                        const unsigned short* __restrict__ A3,
                        void* __restrict__ Cout3) {
  __shared__ __align__(16) unsigned short lA[128 * LROW];
  __shared__ __align__(16) unsigned short lB[128 * LROW];

  int bx = blockIdx.x, by = blockIdx.y;
  if (MODE == 0) {
    if (blockIdx.z == 1) { B = B2; Cout = Cout2; alpha = alpha2; }
    else if (blockIdx.z == 2) {
      B = A; A = A3; Cout = Cout3; alpha = 1.0f; N = SEQ;
      int tmp = bx; bx = by; by = tmp;   // m-tiles over 768, n-tiles over 8192
    }
  }
  const int kOff = (MODE == 2) ? blockIdx.z * kChunk : 0;

  const int t    = threadIdx.x;
  const int w    = t >> 6;
  const int l    = t & 63;
  const int r32  = l & 31;
  const int kh   = l >> 5;
  const int m0   = bx * 128;
  const int n0   = by * 128;
  const int wm   = (w & 1) * 64;
  const int wn   = (w >> 1) * 64;

  int gOff[4], dOff[4];
#pragma unroll
  for (int h = 0; h < 4; ++h) {
    int c   = t + (h << 8);
    int row = c >> 3;
    int j   = c & 7;
    gOff[h] = row * K + ((j ^ (row & 7)) << 3);
    dOff[h] = c << 3;
  }
  const unsigned short* Abase = A + (size_t)m0 * K + kOff;
  const unsigned short* Bbase = B + (size_t)n0 * K + kOff;

  const int xr = (r32 & 7) << 3;
  int offA0[4], offA1[4], offB0[4], offB1[4];
#pragma unroll
  for (int ks = 0; ks < 4; ++ks) {
    const int gg = (((ks << 1) | kh) << 3) ^ xr;
    offA0[ks] = (wm      + r32) * LROW + gg;
    offA1[ks] = (wm + 32 + r32) * LROW + gg;
    offB0[ks] = (wn      + r32) * LROW + gg;
    offB1[ks] = (wn + 32 + r32) * LROW + gg;
  }

  f32x16 acc[2][2] = {};
  const int nk = kChunk >> 6;

#pragma unroll
  for (int h = 0; h < 4; ++h) gload16(Abase + gOff[h], &lA[dOff[h]]);
#pragma unroll
  for (int h = 0; h < 4; ++h) gload16(Bbase + gOff[h], &lB[dOff[h]]);
  __syncthreads();

  for (int kt = 0; kt < nk; ++kt) {
#pragma unroll
    for (int ks = 0; ks < 4; ++ks) {
      bf16x8 a0 = *(const bf16x8*)&lA[offA0[ks]];
      bf16x8 a1 = *(const bf16x8*)&lA[offA1[ks]];
      bf16x8 b0 = *(const bf16x8*)&lB[offB0[ks]];
      bf16x8 b1 = *(const bf16x8*)&lB[offB1[ks]];
      acc[0][0] = __builtin_amdgcn_mfma_f32_32x32x16_bf16(a0, b0, acc[0][0], 0, 0, 0);
      acc[0][1] = __builtin_amdgcn_mfma_f32_32x32x16_bf16(a0, b1, acc[0][1], 0, 0, 0);
      acc[1][0] = __builtin_amdgcn_mfma_f32_32x32x16_bf16(a1, b0, acc[1][0], 0, 0, 0);
      acc[1][1] = __builtin_amdgcn_mfma_f32_32x32x16_bf16(a1, b1, acc[1][1], 0, 0, 0);
    }
    if (kt + 1 < nk) {
      __syncthreads();
      const int ko = (kt + 1) << 6;
#pragma unroll
      for (int h = 0; h < 4; ++h) gload16(Abase + gOff[h] + ko, &lA[dOff[h]]);
#pragma unroll
      for (int h = 0; h < 4; ++h) gload16(Bbase + gOff[h] + ko, &lB[dOff[h]]);
      __syncthreads();
    }
  }

  if (MODE == 0) {
    unsigned short* C = (unsigned short*)Cout;
#pragma unroll
    for (int mi = 0; mi < 2; ++mi)
#pragma unroll
      for (int reg = 0; reg < 16; ++reg) {
        int m = m0 + wm + mi * 32 + (reg & 3) + ((reg >> 2) << 3) + (kh << 2);
#pragma unroll
        for (int ni = 0; ni < 2; ++ni) {
          int n = n0 + wn + ni * 32 + r32;
          C[(size_t)m * N + n] = f2bf(acc[mi][ni][reg] * alpha);
        }
      }
  } else if (MODE == 2) {
    float* C = (float*)Cout;
#pragma unroll
    for (int mi = 0; mi < 2; ++mi)
#pragma unroll
      for (int reg = 0; reg < 16; ++reg) {
        int m = m0 + wm + mi * 32 + (reg & 3) + ((reg >> 2) << 3) + (kh << 2);
        float inv = 1.0f / rowsum[m];
#pragma unroll
        for (int ni = 0; ni < 2; ++ni) {
          int n = n0 + wn + ni * 32 + r32;
          atomicAdd(&C[(size_t)m * N + n], acc[mi][ni][reg] * inv);
        }
      }
  }
}

extern "C" void kernel_launch(void* const* d_in, const int* in_sizes, int n_in,
                              void* d_out, int out_size, void* d_ws, size_t ws_size,
                              hipStream_t stream) {
  const float* x  = (const float*)d_in[0];
  const float* Wq = (const float*)d_in[1];
  const float* Wk = (const float*)d_in[2];
  const float* Wv = (const float*)d_in[3];

  char* ws = (char*)d_ws;
  unsigned short* xb     = (unsigned short*)(ws + 0);
  unsigned short* Qb     = (unsigned short*)(ws + 12582912);
  unsigned short* Kb     = (unsigned short*)(ws + 25165824);
  unsigned short* Vtb    = (unsigned short*)(ws + 37748736);
  unsigned short* wqb    = (unsigned short*)(ws + 50331648);
  unsigned short* wkb    = (unsigned short*)(ws + 51511296);
  unsigned short* wvb    = (unsigned short*)(ws + 52690944);
  float*          rowsum = (float*)(ws + 53870592);
  unsigned short* Pb     = (unsigned short*)(ws + 53903360);
  const size_t need = 53903360u + (size_t)SEQ * SEQ * 2u;
  if (ws_size < need) return;

  hipMemsetAsync(rowsum, 0, SEQ * sizeof(float), stream);
  hipMemsetAsync(d_out, 0, (size_t)out_size * sizeof(float), stream);

  // K0: all converts, one launch (NX + 3*NW float4s)
  const int n4_total = SEQ * DMODEL / 4 + 3 * (DMODEL * DMODEL / 4);
  convert_all<<<(n4_total + 255) / 256, 256, 0, stream>>>(
      x, Wq, Wk, Wv, xb, wqb, wkb, wvb);

  const float alpha_q = 0.03608439182435161f;  // 1/sqrt(768)
  // K1: fused Q/K/Vt projections, one launch (64 x 6 x 3 = 1152 blocks)
  gemm_bt<0><<<dim3(SEQ / 128, DMODEL / 128, 3), dim3(256), 0, stream>>>(
      xb, wqb, Qb, SEQ, DMODEL, DMODEL, alpha_q, nullptr, DMODEL,
      wkb, Kb, 1.0f, wvb, Vtb);
  // K2: 256^2 8-phase, exp + rowsum (1024 blocks)
  gemm256_exp<<<dim3(SEQ / 256, SEQ / 256), dim3(512), 0, stream>>>(
      Qb, Kb, Pb, SEQ, DMODEL, rowsum);
  // K3: 128^2 engine, split-K x4 (64 x 6 x 4 = 1536 blocks, 4-resident)
  gemm_bt<2><<<dim3(SEQ / 128, DMODEL / 128, KSPLIT), dim3(256), 0, stream>>>(
      Pb, Vtb, d_out, SEQ, DMODEL, SEQ, 1.0f, rowsum, SEQ / KSPLIT,
      nullptr, nullptr, 1.0f, nullptr, nullptr);
}